// Round 4
// baseline (124.686 us; speedup 1.0000x reference)
//
#include <hip/hip_runtime.h>

#define HDIM 256
#define NBLK 1024            // colsum blocks
#define NREP 8               // histogram replicas (one per XCD, blockIdx&7 proxy)
#define FXSCALE 16777216.0f  // 2^24 fixed-point for deterministic cross-block float accumulation
#define FXINV   5.9604644775390625e-8f

// Stage 0: zero counts replicas + acc64 + ticket (contiguous region).
__global__ void k_zero(uint4* __restrict__ p, int n4) {
    int i = blockIdx.x * blockDim.x + threadIdx.x;
    if (i < n4) p[i] = make_uint4(0u, 0u, 0u, 0u);
}

// Stage 1: histogram of src indices into 8 XCD-local replicas (int atomics -> deterministic).
__global__ void k_count(const int4* __restrict__ src4, const int* __restrict__ src,
                        int E, int N, unsigned int* __restrict__ counts8) {
    int i = blockIdx.x * blockDim.x + threadIdx.x;
    unsigned int* c = counts8 + (size_t)(blockIdx.x & (NREP - 1)) * N;
    int E4 = E >> 2;
    if (i < E4) {
        int4 v = src4[i];
        atomicAdd(&c[v.x], 1u); atomicAdd(&c[v.y], 1u);
        atomicAdd(&c[v.z], 1u); atomicAdd(&c[v.w], 1u);
    }
    if (i < (E & 3)) {  // tail (E not multiple of 4)
        atomicAdd(&counts8[src[(E4 << 2) + i]], 1u);
    }
}

// Stage 2 (fused): weighted column-sum of x_src -> int64 fixed-point global accumulate;
// last block converts and computes v = R @ left_sum.
__global__ __launch_bounds__(256)
void k_colsum_matvec(const float4* __restrict__ x4,
                     const unsigned int* __restrict__ counts8, int N,
                     const float* __restrict__ Rm,
                     unsigned long long* __restrict__ acc64,
                     unsigned int* __restrict__ ticket,
                     float* __restrict__ v) {
    const int colgrp = threadIdx.x & 63;   // float4 slot within row
    const int rowOff = threadIdx.x >> 6;   // 0..3
    float4 acc = make_float4(0.f, 0.f, 0.f, 0.f);
    for (int n = blockIdx.x * 4 + rowOff; n < N; n += NBLK * 4) {
        float c = 0.f;
        #pragma unroll
        for (int r = 0; r < NREP; ++r) c += (float)counts8[(size_t)r * N + n];
        float4 x = x4[(size_t)n * 64 + colgrp];
        acc.x += c * x.x; acc.y += c * x.y; acc.z += c * x.z; acc.w += c * x.w;
    }
    __shared__ float s[4 * HDIM];
    int col = colgrp * 4;
    s[rowOff * HDIM + col + 0] = acc.x;
    s[rowOff * HDIM + col + 1] = acc.y;
    s[rowOff * HDIM + col + 2] = acc.z;
    s[rowOff * HDIM + col + 3] = acc.w;
    __syncthreads();
    const int tid = threadIdx.x;
    float part = s[tid] + s[HDIM + tid] + s[2 * HDIM + tid] + s[3 * HDIM + tid];
    // deterministic accumulation: integer atomics are order-independent
    long long q = (long long)llrintf(part * FXSCALE);
    atomicAdd(&acc64[tid], (unsigned long long)q);
    __threadfence();           // make this thread's atomic visible before ticket
    __syncthreads();           // all threads of block fenced
    __shared__ unsigned int lastflag;
    if (tid == 0) lastflag = (atomicAdd(ticket, 1u) == NBLK - 1) ? 1u : 0u;
    __syncthreads();
    if (lastflag) {
        __threadfence();
        __shared__ float lss[HDIM];
        // atomic read-back guarantees coherent view of other XCDs' adds
        long long qv = (long long)atomicAdd(&acc64[tid], 0ull);
        lss[tid] = (float)qv * FXINV;
        __syncthreads();
        const float4* R4 = (const float4*)(Rm + (size_t)tid * HDIM);
        float a = 0.f;
        #pragma unroll
        for (int j = 0; j < 64; ++j) {
            float4 r = R4[j];
            a += r.x * lss[4 * j] + r.y * lss[4 * j + 1] + r.z * lss[4 * j + 2] + r.w * lss[4 * j + 3];
        }
        v[tid] = a;
    }
}

// Stage 3: t[n] = dot(x_trg[n], v). One wave per row, float4 loads (1KB coalesced per row).
__global__ void k_rowdot(const float4* __restrict__ x4, const float* __restrict__ v,
                         int N, float* __restrict__ t) {
    __shared__ float4 vs[64];
    int tid = threadIdx.x;
    if (tid < 64) vs[tid] = ((const float4*)v)[tid];
    __syncthreads();
    int lane = tid & 63;
    int wid = tid >> 6;            // 4 waves per block = 4 rows
    int n = blockIdx.x * 4 + wid;
    if (n < N) {
        float4 x = x4[(size_t)n * 64 + lane];
        float4 vv = vs[lane];
        float d = x.x * vv.x + x.y * vv.y + x.z * vv.z + x.w * vv.w;
        #pragma unroll
        for (int off = 32; off > 0; off >>= 1) d += __shfl_down(d, off, 64);
        if (lane == 0) t[n] = d;
    }
}

// Stage 4: out[e] = t[trg[e]] — vectorized gather from the L2-resident 200KB table.
__global__ void k_gather(const int4* __restrict__ trg4, const int* __restrict__ trg, int E,
                         const float* __restrict__ t,
                         float4* __restrict__ out4, float* __restrict__ out) {
    int i = blockIdx.x * blockDim.x + threadIdx.x;
    int E4 = E >> 2;
    if (i < E4) {
        int4 v = trg4[i];
        out4[i] = make_float4(t[v.x], t[v.y], t[v.z], t[v.w]);
    }
    if (i < (E & 3)) {
        int e = (E4 << 2) + i;
        out[e] = t[trg[e]];
    }
}

extern "C" void kernel_launch(void* const* d_in, const int* in_sizes, int n_in,
                              void* d_out, int out_size, void* d_ws, size_t ws_size,
                              hipStream_t stream) {
    const float* x_src = (const float*)d_in[0];
    const float* x_trg = (const float*)d_in[1];
    const float* Rm    = (const float*)d_in[2];
    const int*   edge  = (const int*)d_in[3];   // [0..E)=src, [E..2E)=trg
    float* out = (float*)d_out;

    const int N_src = in_sizes[0] / HDIM;
    const int N_trg = in_sizes[1] / HDIM;
    const int E     = in_sizes[3] / 2;

    // Workspace carve-out (256B-aligned slices).
    char* ws = (char*)d_ws;
    size_t off = 0;
    auto alloc = [&](size_t bytes) -> void* {
        void* p = ws + off;
        off = (off + bytes + 255) & ~(size_t)255;
        return p;
    };
    // Contiguous zero-region: counts8 | acc64 | ticket (sizes all 16B-multiples).
    const size_t counts_bytes = (size_t)NREP * N_src * sizeof(unsigned int);   // 1.6 MB
    const size_t zbytes = counts_bytes + HDIM * sizeof(unsigned long long) + 256;
    unsigned int* zbase = (unsigned int*)alloc(zbytes);
    unsigned int* counts8 = zbase;
    unsigned long long* acc64 = (unsigned long long*)((char*)zbase + counts_bytes);
    unsigned int* ticket = (unsigned int*)(acc64 + HDIM);
    float* v = (float*)alloc(HDIM * sizeof(float));
    float* t = (float*)alloc((size_t)N_trg * sizeof(float));
    (void)ws_size; (void)n_in; (void)out_size;

    const int n4 = (int)(zbytes / 16);
    k_zero<<<(n4 + 255) / 256, 256, 0, stream>>>((uint4*)zbase, n4);

    const int E4 = E >> 2;
    const int cntThreads = (E4 > 0 ? E4 : 1);
    k_count<<<(cntThreads + 255) / 256, 256, 0, stream>>>(
        (const int4*)edge, edge, E, N_src, counts8);

    k_colsum_matvec<<<NBLK, 256, 0, stream>>>(
        (const float4*)x_src, counts8, N_src, Rm, acc64, ticket, v);

    k_rowdot<<<(N_trg + 3) / 4, 256, 0, stream>>>((const float4*)x_trg, v, N_trg, t);

    k_gather<<<(cntThreads + 255) / 256, 256, 0, stream>>>(
        (const int4*)(edge + E), edge + E, E, t, (float4*)out, out);
}

// Round 5
// 67.964 us; speedup vs baseline: 1.8346x; 1.8346x over previous
//
#include <hip/hip_runtime.h>

#define HDIM 256
#define NBLK 1024            // colsum blocks (compile-time so the reducer fully unrolls)
#define NREP 8               // histogram replicas (one per XCD, blockIdx&7 proxy)

// Stage 0: zero the counts replicas.
__global__ void k_zero(uint4* __restrict__ p, int n4) {
    int i = blockIdx.x * blockDim.x + threadIdx.x;
    if (i < n4) p[i] = make_uint4(0u, 0u, 0u, 0u);
}

// Stage 1: histogram of src indices into 8 XCD-local replicas.
// Spread-address atomics (~6 hits/address/replica), L2-local per XCD -> fast.
__global__ void k_count(const int4* __restrict__ src4, const int* __restrict__ src,
                        int E, int N, unsigned int* __restrict__ counts8) {
    int i = blockIdx.x * blockDim.x + threadIdx.x;
    unsigned int* c = counts8 + (size_t)(blockIdx.x & (NREP - 1)) * N;
    int E4 = E >> 2;
    if (i < E4) {
        int4 v = src4[i];
        atomicAdd(&c[v.x], 1u); atomicAdd(&c[v.y], 1u);
        atomicAdd(&c[v.z], 1u); atomicAdd(&c[v.w], 1u);
    }
    if (i < (E & 3)) {  // tail when E not divisible by 4
        atomicAdd(&counts8[src[(E4 << 2) + i]], 1u);
    }
}

// Stage 2: partial weighted column sums: partials[b][h] = sum over this block's rows
// of (sum_r counts8[r][n]) * x_src[n][h]. Pure global stores for the partials --
// NO cross-block atomics (round 4 showed 262K atomics onto 32 lines costs ~90us).
__global__ __launch_bounds__(256)
void k_colsum_partial(const float4* __restrict__ x4,
                      const unsigned int* __restrict__ counts8,
                      int N, float* __restrict__ partials) {
    const int colgrp = threadIdx.x & 63;   // float4 slot within row
    const int rowOff = threadIdx.x >> 6;   // 0..3
    float4 acc = make_float4(0.f, 0.f, 0.f, 0.f);
    for (int n = blockIdx.x * 4 + rowOff; n < N; n += NBLK * 4) {
        float c = 0.f;
        #pragma unroll
        for (int r = 0; r < NREP; ++r) c += (float)counts8[(size_t)r * N + n];  // wave-uniform broadcasts
        float4 x = x4[(size_t)n * 64 + colgrp];
        acc.x += c * x.x; acc.y += c * x.y; acc.z += c * x.z; acc.w += c * x.w;
    }
    __shared__ float s[4 * HDIM];
    int col = colgrp * 4;
    s[rowOff * HDIM + col + 0] = acc.x;
    s[rowOff * HDIM + col + 1] = acc.y;
    s[rowOff * HDIM + col + 2] = acc.z;
    s[rowOff * HDIM + col + 3] = acc.w;
    __syncthreads();
    int tid = threadIdx.x;
    partials[(size_t)blockIdx.x * HDIM + tid] =
        s[tid] + s[HDIM + tid] + s[2 * HDIM + tid] + s[3 * HDIM + tid];
}

// Stage 3 (fused): left_sum[h] = sum_b partials[b][h]; v = R @ left_sum.
// One block, 1024 threads = (q=0..3) x (h=0..255); compile-time trips, deep unroll.
__global__ __launch_bounds__(1024)
void k_reduce_matvec(const float* __restrict__ partials,
                     const float* __restrict__ Rm,
                     float* __restrict__ v) {
    __shared__ float red[4][HDIM];
    __shared__ float lss[HDIM];
    const int tid = threadIdx.x;
    const int h = tid & (HDIM - 1);
    const int q = tid >> 8;   // 0..3

    const float* p = partials + (size_t)q * (NBLK / 4) * HDIM + h;
    float acc = 0.f;
    #pragma unroll 16
    for (int b = 0; b < NBLK / 4; ++b) acc += p[(size_t)b * HDIM];
    red[q][h] = acc;
    __syncthreads();
    if (q == 0) lss[h] = red[0][h] + red[1][h] + red[2][h] + red[3][h];
    __syncthreads();

    const float4* R4 = (const float4*)(Rm + (size_t)h * HDIM);
    float a = 0.f;
    #pragma unroll
    for (int j = q * 16; j < q * 16 + 16; ++j) {
        float4 r = R4[j];
        a += r.x * lss[4 * j] + r.y * lss[4 * j + 1] + r.z * lss[4 * j + 2] + r.w * lss[4 * j + 3];
    }
    red[q][h] = a;
    __syncthreads();
    if (q == 0) v[h] = red[0][h] + red[1][h] + red[2][h] + red[3][h];
}

// Stage 4: t[n] = dot(x_trg[n], v). One wave per row, float4 loads (1KB coalesced per row).
__global__ void k_rowdot(const float4* __restrict__ x4, const float* __restrict__ v,
                         int N, float* __restrict__ t) {
    __shared__ float4 vs[64];
    int tid = threadIdx.x;
    if (tid < 64) vs[tid] = ((const float4*)v)[tid];
    __syncthreads();
    int lane = tid & 63;
    int wid = tid >> 6;            // 4 waves per block = 4 rows
    int n = blockIdx.x * 4 + wid;
    if (n < N) {
        float4 x = x4[(size_t)n * 64 + lane];
        float4 vv = vs[lane];
        float d = x.x * vv.x + x.y * vv.y + x.z * vv.z + x.w * vv.w;
        #pragma unroll
        for (int off = 32; off > 0; off >>= 1) d += __shfl_down(d, off, 64);
        if (lane == 0) t[n] = d;
    }
}

// Stage 5: out[e] = t[trg[e]] — vectorized gather from the L2-resident 200KB table.
__global__ void k_gather(const int4* __restrict__ trg4, const int* __restrict__ trg, int E,
                         const float* __restrict__ t,
                         float4* __restrict__ out4, float* __restrict__ out) {
    int i = blockIdx.x * blockDim.x + threadIdx.x;
    int E4 = E >> 2;
    if (i < E4) {
        int4 v = trg4[i];
        out4[i] = make_float4(t[v.x], t[v.y], t[v.z], t[v.w]);
    }
    if (i < (E & 3)) {
        int e = (E4 << 2) + i;
        out[e] = t[trg[e]];
    }
}

extern "C" void kernel_launch(void* const* d_in, const int* in_sizes, int n_in,
                              void* d_out, int out_size, void* d_ws, size_t ws_size,
                              hipStream_t stream) {
    const float* x_src = (const float*)d_in[0];
    const float* x_trg = (const float*)d_in[1];
    const float* Rm    = (const float*)d_in[2];
    const int*   edge  = (const int*)d_in[3];   // [0..E)=src, [E..2E)=trg
    float* out = (float*)d_out;

    const int N_src = in_sizes[0] / HDIM;
    const int N_trg = in_sizes[1] / HDIM;
    const int E     = in_sizes[3] / 2;

    // Workspace carve-out (256B-aligned slices).
    char* ws = (char*)d_ws;
    size_t off = 0;
    auto alloc = [&](size_t bytes) -> void* {
        void* p = ws + off;
        off = (off + bytes + 255) & ~(size_t)255;
        return p;
    };
    unsigned int* counts8 = (unsigned int*)alloc((size_t)NREP * N_src * sizeof(unsigned int)); // 1.6MB
    float* partials       = (float*)alloc((size_t)NBLK * HDIM * sizeof(float));                // 1MB
    float* v              = (float*)alloc(HDIM * sizeof(float));
    float* t              = (float*)alloc((size_t)N_trg * sizeof(float));
    (void)ws_size; (void)n_in; (void)out_size;

    const int n4 = (int)(((size_t)NREP * N_src * sizeof(unsigned int)) / 16);
    k_zero<<<(n4 + 255) / 256, 256, 0, stream>>>((uint4*)counts8, n4);

    const int E4 = E >> 2;
    const int cntThreads = (E4 > 0 ? E4 : 1);
    k_count<<<(cntThreads + 255) / 256, 256, 0, stream>>>(
        (const int4*)edge, edge, E, N_src, counts8);

    k_colsum_partial<<<NBLK, 256, 0, stream>>>(
        (const float4*)x_src, counts8, N_src, partials);

    k_reduce_matvec<<<1, 1024, 0, stream>>>(partials, Rm, v);

    k_rowdot<<<(N_trg + 3) / 4, 256, 0, stream>>>((const float4*)x_trg, v, N_trg, t);

    k_gather<<<(cntThreads + 255) / 256, 256, 0, stream>>>(
        (const int4*)(edge + E), edge + E, E, t, (float4*)out, out);
}